// Round 8
// baseline (405.318 us; speedup 1.0000x reference)
//
#include <hip/hip_runtime.h>

#define NB 32
#define NT 2048
#define ND 1024
#define NU 1024
#define NM (NB*NT)   // 65536 rows

using f32x4 = __attribute__((ext_vector_type(4))) float;
using s16x8 = __attribute__((ext_vector_type(8))) short;

#define BAR()   asm volatile("s_barrier" ::: "memory")
#define VMC(n)  asm volatile("s_waitcnt vmcnt(" #n ")" ::: "memory")
#define SB0()   __builtin_amdgcn_sched_barrier(0)

__device__ __forceinline__ unsigned short f2bf(float f) {
  unsigned u = __builtin_bit_cast(unsigned, f);
  u = u + 0x7fffu + ((u >> 16) & 1u);   // round-to-nearest-even
  return (unsigned short)(u >> 16);
}

__device__ __forceinline__ unsigned cvtpk(float lo, float hi) {
  unsigned r;
  asm("v_cvt_pk_bf16_f32 %0, %1, %2" : "=v"(r) : "v"(lo), "v"(hi));
  return r;
}

__device__ __forceinline__ void gload_lds16(const void* g, void* l) {
  __builtin_amdgcn_global_load_lds(
      (const __attribute__((address_space(1))) unsigned int*)g,
      (__attribute__((address_space(3))) unsigned int*)l, 16, 0, 0);
}

__device__ __forceinline__ float tanh_fast(float x) {
  float e = __expf(2.0f * x);
  return 1.0f - 2.0f * __builtin_amdgcn_rcpf(e + 1.0f);
}

// ---- A tile: 128 rows x 32 k f32 (16KB). LDS[r][c] = G[r][c ^ (r&7)], c = 16B chunk.
// Wave-linear dest: lane covers row (lane>>3), chunk (lane&7); row&7 == lane>>3.
__device__ __forceinline__ void stageA(const float* g, float* l, int w, int lane) {
  int rloc = lane >> 3;
  int gc = (lane & 7) ^ rloc;
#pragma unroll
  for (int i = 0; i < 2; ++i) {
    int rb = (w * 2 + i) * 8;
    gload_lds16(g + (size_t)(rb + rloc) * 1024 + gc * 4, l + rb * 32);
  }
}

// ---- B tile: 256 rows x 32 k bf16 (16KB). LDS[r][c] = G[r][c ^ ((r>>1)&3)].
__device__ __forceinline__ void stageB(const unsigned short* g, unsigned short* l,
                                       int w, int lane) {
  int l2 = lane >> 2;
  int gc = (lane & 3) ^ ((lane >> 3) & 3);
#pragma unroll
  for (int i = 0; i < 2; ++i) {
    int rblk = w * 2 + i;
    gload_lds16(g + (size_t)(rblk * 16 + l2) * 1024 + gc * 8, l + rblk * 512);
  }
}

// B fragment: 16B at (row, k-chunk lg), chunk XOR ((row>>1)&3)
__device__ __forceinline__ s16x8 frag_read(const unsigned short* buf, int row, int lg) {
  int cr = lg ^ ((row >> 1) & 3);
  return *(const s16x8*)(buf + row * 32 + cr * 8);
}

// A fragment from f32 LDS: 8 f32 (2 x b128) -> 4 cvt_pk -> s16x8
__device__ __forceinline__ s16x8 fragA_f32(const float* buf, int row, int lg) {
  int r7 = row & 7;
  int c0 = (lg * 2) ^ r7, c1 = (lg * 2 + 1) ^ r7;
  f32x4 x = *(const f32x4*)(buf + row * 32 + c0 * 4);
  f32x4 y = *(const f32x4*)(buf + row * 32 + c1 * 4);
  uint4 u = make_uint4(cvtpk(x[0], x[1]), cvtpk(x[2], x[3]),
                       cvtpk(y[0], y[1]), cvtpk(y[2], y[3]));
  return __builtin_bit_cast(s16x8, u);
}

// One K-tile, one phase: VMC(4) [T+1 landed, 2 bodies old] -> BAR -> stage(T+3)
// -> pre-read frags(T+1) -> MFMA(T). Staging after BAR = race-free vs T-1 readers.
template<bool PRE, bool ST, int VM>
__device__ __forceinline__ void tile_one(
    int kt, const float* gA, const unsigned short* gB,
    float* sAf, unsigned short* sB, f32x4 (&acc)[4][4],
    s16x8 (&fa)[4], s16x8 (&fb)[4], s16x8 (&nfa)[4], s16x8 (&nfb)[4],
    int w, int lane, int wr, int wc, int l15, int lg) {
  if constexpr (VM == 4) { VMC(4); }
  else if constexpr (VM == 0) { VMC(0); }
  BAR();
  if (ST) {
    stageA(gA + (size_t)(kt + 3) * 32, sAf + ((kt + 3) & 3) * 4096, w, lane);
    stageB(gB + (size_t)(kt + 3) * 32, sB + ((kt + 3) & 3) * 8192, w, lane);
  }
  if (PRE) {
    const float* qA = sAf + ((kt + 1) & 3) * 4096;
    const unsigned short* qB = sB + ((kt + 1) & 3) * 8192;
#pragma unroll
    for (int i = 0; i < 4; ++i) nfa[i] = fragA_f32(qA, wr * 64 + i * 16 + l15, lg);
#pragma unroll
    for (int n = 0; n < 4; ++n) nfb[n] = frag_read(qB, wc * 64 + n * 16 + l15, lg);
  }
  SB0();
  __builtin_amdgcn_s_setprio(1);
#pragma unroll
  for (int m = 0; m < 4; ++m)
#pragma unroll
    for (int n = 0; n < 4; ++n)
      acc[m][n] = __builtin_amdgcn_mfma_f32_16x16x32_bf16(fa[m], fb[n], acc[m][n], 0, 0, 0);
  __builtin_amdgcn_s_setprio(0);
}

// 128x256 tile, BK=32, quad-buffered, A f32-in-LDS (cvt at frag read), no cvt kernel.
__global__ __launch_bounds__(512, 2) void k_score_gemmf(
    const float* __restrict__ values, const unsigned short* __restrict__ W2t,
    const float* __restrict__ add2, const float* __restrict__ Vk,
    float* __restrict__ score_part) {
  __shared__ float sAf[16384];            // 4 bufs x 128 x 32 f32 = 64KB
  __shared__ unsigned short sB[32768];    // 4 bufs x 256 x 32 bf16 = 64KB
  const int tid = threadIdx.x;
  const int w = tid >> 6, lane = tid & 63;
  const int wr = w >> 2, wc = w & 3;      // 2M x 4N waves, wave-tile 64x64
  const int l15 = lane & 15, lg = lane >> 4;

  const int L = blockIdx.x;               // 2048 blocks
  const int g = (L & 7) * 256 + (L >> 3); // XCD-contiguous
  const int mtile = g >> 2, ntile = g & 3;

  const float* gA = values + ((size_t)mtile << 17);          // 128 rows x 1024
  const unsigned short* gB = W2t + ((size_t)ntile << 18);    // 256 rows x 1024

  f32x4 acc[4][4] = {};
  s16x8 fa0[4], fb0[4], fa1[4], fb1[4];

  // Prologue: stage tiles 0,1,2; retire tile0 (VMC(8)); pre-read frags(0).
  stageA(gA, sAf, w, lane);                   stageB(gB, sB, w, lane);
  stageA(gA + 32, sAf + 4096, w, lane);       stageB(gB + 32, sB + 8192, w, lane);
  stageA(gA + 64, sAf + 8192, w, lane);       stageB(gB + 64, sB + 16384, w, lane);
  VMC(8);
  BAR();
#pragma unroll
  for (int i = 0; i < 4; ++i) fa0[i] = fragA_f32(sAf, wr * 64 + i * 16 + l15, lg);
#pragma unroll
  for (int n = 0; n < 4; ++n) fb0[n] = frag_read(sB, wc * 64 + n * 16 + l15, lg);

#pragma unroll 1
  for (int kt = 0; kt < 28; kt += 2) {
    tile_one<true, true, 4>(kt,     gA, gB, sAf, sB, acc, fa0, fb0, fa1, fb1, w, lane, wr, wc, l15, lg);
    tile_one<true, true, 4>(kt + 1, gA, gB, sAf, sB, acc, fa1, fb1, fa0, fb0, w, lane, wr, wc, l15, lg);
  }
  tile_one<true,  true,  4>(28, gA, gB, sAf, sB, acc, fa0, fb0, fa1, fb1, w, lane, wr, wc, l15, lg);
  tile_one<true,  false, 4>(29, gA, gB, sAf, sB, acc, fa1, fb1, fa0, fb0, w, lane, wr, wc, l15, lg);
  tile_one<true,  false, 0>(30, gA, gB, sAf, sB, acc, fa0, fb0, fa1, fb1, w, lane, wr, wc, l15, lg);
  tile_one<false, false,-1>(31, gA, gB, sAf, sB, acc, fa1, fb1, fa0, fb0, w, lane, wr, wc, l15, lg);

  // Epilogue: x = acc + add2[b][u]; row-sum of tanh(x)*Vk[u] over this 256-col slab
  const int b = mtile >> 4;               // (mtile*128)/2048, block-uniform
  float vks[4], adds[4];
#pragma unroll
  for (int n = 0; n < 4; ++n) {
    int u = ntile * 256 + wc * 64 + n * 16 + l15;
    vks[n] = Vk[u];
    adds[n] = add2[(b << 10) + u];
  }
  __syncthreads();
  float* part = (float*)sAf;              // [4][128]
#pragma unroll
  for (int m = 0; m < 4; ++m) {
#pragma unroll
    for (int j = 0; j < 4; ++j) {
      float s = 0.f;
#pragma unroll
      for (int n = 0; n < 4; ++n) {
        float x = acc[m][n][j] + adds[n];
        s = fmaf(tanh_fast(x), vks[n], s);
      }
#pragma unroll
      for (int off = 1; off < 16; off <<= 1) s += __shfl_xor(s, off);
      if (l15 == 0) part[wc * 128 + wr * 64 + m * 16 + lg * 4 + j] = s;
    }
  }
  __syncthreads();
  if (tid < 128) {
    float v = part[tid] + part[128 + tid] + part[256 + tid] + part[384 + tid];
    score_part[((size_t)ntile << 16) + mtile * 128 + tid] = v;
  }
}

// add2[b][u] = query[b]·W1_k[:,u] + W1_b[u] + W2_b[u]
__global__ void k_qproj(const float* __restrict__ q, const float* __restrict__ W1,
                        const float* __restrict__ W1b, const float* __restrict__ W2b,
                        float* __restrict__ add2) {
  int u = blockIdx.x * 256 + threadIdx.x;
  int b = blockIdx.y;
  const float* qr = q + (b << 10);
  float s = 0.f;
#pragma unroll 8
  for (int d = 0; d < ND; ++d) s = fmaf(qr[d], W1[d * NU + u], s);
  add2[(b << 10) + u] = s + W1b[u] + W2b[u];
}

// W2_k [D][U] f32 -> W2t [U][D] bf16
__global__ void k_w2t(const float* __restrict__ W2, unsigned short* __restrict__ W2t) {
  __shared__ unsigned short tile[64][65];
  int bu = blockIdx.x * 64, bd = blockIdx.y * 64;
  int x = threadIdx.x & 63, y4 = threadIdx.x >> 6;
#pragma unroll
  for (int r = 0; r < 16; ++r) {
    int dl = y4 * 16 + r;
    tile[x][dl] = f2bf(W2[(size_t)(bd + dl) * NU + bu + x]);
  }
  __syncthreads();
#pragma unroll
  for (int r = 0; r < 16; ++r) {
    int ul = y4 * 16 + r;
    W2t[(size_t)(bu + ul) * ND + bd + x] = tile[ul][x];
  }
}

// softmax over T per batch; sums 4 N-tile partials first (deterministic)
__global__ void k_softmax(const float* __restrict__ sp, float* __restrict__ w) {
  __shared__ float redm[4], reds[4];
  int b = blockIdx.x, tid = threadIdx.x;
  float s[8];
  float mx = -1e30f;
#pragma unroll
  for (int i = 0; i < 8; ++i) {
    int t = i * 256 + tid;
    float v = 0.f;
#pragma unroll
    for (int p = 0; p < 4; ++p) v += sp[((size_t)p << 16) + (b << 11) + t];
    s[i] = v;
    mx = fmaxf(mx, v);
  }
#pragma unroll
  for (int o = 1; o < 64; o <<= 1) mx = fmaxf(mx, __shfl_xor(mx, o));
  if ((tid & 63) == 0) redm[tid >> 6] = mx;
  __syncthreads();
  mx = fmaxf(fmaxf(redm[0], redm[1]), fmaxf(redm[2], redm[3]));
  float sum = 0.f;
#pragma unroll
  for (int i = 0; i < 8; ++i) { s[i] = __expf(s[i] - mx); sum += s[i]; }
#pragma unroll
  for (int o = 1; o < 64; o <<= 1) sum += __shfl_xor(sum, o);
  if ((tid & 63) == 0) reds[tid >> 6] = sum;
  __syncthreads();
  float inv = 1.0f / (reds[0] + reds[1] + reds[2] + reds[3]);
#pragma unroll
  for (int i = 0; i < 8; ++i) w[(b << 11) + i * 256 + tid] = s[i] * inv;
}

// context partials: part[tc][b][d] = sum_{t in chunk} w[b][t]*values[b][t][d] (float4)
__global__ void k_context(const float* __restrict__ values, const float* __restrict__ wv,
                          float* __restrict__ part) {
  int d4 = threadIdx.x;
  int b = blockIdx.y, tc = blockIdx.z;
  const float4* vb = (const float4*)(values + ((size_t)b << 21) + ((size_t)tc << 18)) + d4;
  const float* wb = wv + (b << 11) + (tc << 8);
  float ax = 0.f, ay = 0.f, az = 0.f, aw = 0.f;
#pragma unroll 4
  for (int t = 0; t < 256; ++t) {
    float4 v = vb[(size_t)t << 8];
    float wt = wb[t];
    ax = fmaf(wt, v.x, ax); ay = fmaf(wt, v.y, ay);
    az = fmaf(wt, v.z, az); aw = fmaf(wt, v.w, aw);
  }
  float4* po = (float4*)(part + (((size_t)tc * NB + b) << 10)) + d4;
  *po = make_float4(ax, ay, az, aw);
}

__global__ void k_ctx_reduce(const float* __restrict__ part, float* __restrict__ out) {
  int i = blockIdx.x * 256 + threadIdx.x;  // 32768
  float s = 0.f;
#pragma unroll
  for (int p = 0; p < 8; ++p) s += part[(p << 15) + i];
  out[i] = s;
}

extern "C" void kernel_launch(void* const* d_in, const int* in_sizes, int n_in,
                              void* d_out, int out_size, void* d_ws, size_t ws_size,
                              hipStream_t stream) {
  const float* query  = (const float*)d_in[0];
  const float* values = (const float*)d_in[1];
  const float* W1k    = (const float*)d_in[2];
  const float* W1b    = (const float*)d_in[3];
  const float* W2k    = (const float*)d_in[4];
  const float* W2b    = (const float*)d_in[5];
  const float* Vk     = (const float*)d_in[6];
  // V_b dropped: softmax is shift-invariant.
  float* out = (float*)d_out;
  char* ws = (char*)d_ws;

  size_t off = 0;
  float* add2 = (float*)(ws + off); off += (size_t)NB * NU * 4;          // 128 KB
  float* sp   = (float*)(ws + off); off += (size_t)4 * NM * 4;           // 1 MB
  float* wv   = (float*)(ws + off); off += (size_t)NM * 4;               // 256 KB
  float* ctxp = (float*)(ws + off); off += (size_t)8 * NB * ND * 4;      // 1 MB
  unsigned short* W2t = (unsigned short*)(ws + off); off += (size_t)NU * ND * 2; // 2 MB

  k_qproj<<<dim3(4, 32), 256, 0, stream>>>(query, W1k, W1b, W2b, add2);
  k_w2t<<<dim3(16, 16), 256, 0, stream>>>(W2k, W2t);
  k_score_gemmf<<<dim3(2048), 512, 0, stream>>>(values, W2t, add2, Vk, sp);
  k_softmax<<<dim3(32), 256, 0, stream>>>(sp, wv);
  k_context<<<dim3(1, 32, 8), 256, 0, stream>>>(values, wv, ctxp);
  k_ctx_reduce<<<dim3(128), 256, 0, stream>>>(ctxp, out);
}

// Round 9
// 314.866 us; speedup vs baseline: 1.2873x; 1.2873x over previous
//
#include <hip/hip_runtime.h>

#define NB 32
#define NT 2048
#define ND 1024
#define NU 1024
#define NM (NB*NT)   // 65536 rows

using f32x4 = __attribute__((ext_vector_type(4))) float;
using s16x8 = __attribute__((ext_vector_type(8))) short;

#define BAR()    asm volatile("s_barrier" ::: "memory")
#define LGKM0()  asm volatile("s_waitcnt lgkmcnt(0)" ::: "memory")
#define LGKMC(n) asm volatile("s_waitcnt lgkmcnt(" #n ")" ::: "memory")
#define VMC(n)   asm volatile("s_waitcnt vmcnt(" #n ")" ::: "memory")
#define SB0()    __builtin_amdgcn_sched_barrier(0)

__device__ __forceinline__ unsigned short f2bf(float f) {
  unsigned u = __builtin_bit_cast(unsigned, f);
  u = u + 0x7fffu + ((u >> 16) & 1u);   // round-to-nearest-even
  return (unsigned short)(u >> 16);
}

__device__ __forceinline__ unsigned cvtpk(float lo, float hi) {
  unsigned r;
  asm("v_cvt_pk_bf16_f32 %0, %1, %2" : "=v"(r) : "v"(lo), "v"(hi));
  return r;
}

__device__ __forceinline__ void gload_lds16(const void* g, void* l) {
  __builtin_amdgcn_global_load_lds(
      (const __attribute__((address_space(1))) unsigned int*)g,
      (__attribute__((address_space(3))) unsigned int*)l, 16, 0, 0);
}

__device__ __forceinline__ float tanh_fast(float x) {
  float e = __expf(2.0f * x);
  return 1.0f - 2.0f * __builtin_amdgcn_rcpf(e + 1.0f);
}

// ---- B tile: 256 rows x 32 k bf16 (16KB) via global_load_lds.
// LDS[r][c] = G[r][c ^ ((r>>1)&3)], c = 16B chunk. Proven 0-conflict (R6).
__device__ __forceinline__ void stageB(const unsigned short* g, unsigned short* l,
                                       int w, int lane) {
  int l2 = lane >> 2;
  int gc = (lane & 3) ^ ((lane >> 3) & 3);
#pragma unroll
  for (int i = 0; i < 2; ++i) {
    int rblk = w * 2 + i;
    gload_lds16(g + (size_t)(rblk * 16 + l2) * 1024 + gc * 8, l + rblk * 512);
  }
}

// ---- A f32 loads: thread covers row=tid>>1 (256 rows), khalf=tid&1 (16 f32 each)
__device__ __forceinline__ void loadA(const float* g, int ktile, int row, int khalf,
                                      f32x4 (&f)[4]) {
  const float* p = g + (size_t)row * 1024 + ktile * 32 + khalf * 16;
#pragma unroll
  for (int i = 0; i < 4; ++i) f[i] = *(const f32x4*)(p + 4 * i);
}

// cvt 16 f32 -> 16 bf16, write as two swizzled 16B chunks (same layout as stageB)
__device__ __forceinline__ void cvtwriteA(const f32x4 (&f)[4], unsigned short* bufA,
                                          int row, int khalf) {
  unsigned pk[8];
  pk[0] = cvtpk(f[0][0], f[0][1]); pk[1] = cvtpk(f[0][2], f[0][3]);
  pk[2] = cvtpk(f[1][0], f[1][1]); pk[3] = cvtpk(f[1][2], f[1][3]);
  pk[4] = cvtpk(f[2][0], f[2][1]); pk[5] = cvtpk(f[2][2], f[2][3]);
  pk[6] = cvtpk(f[3][0], f[3][1]); pk[7] = cvtpk(f[3][2], f[3][3]);
  int s = (row >> 1) & 3;
  int c0 = (khalf * 2) ^ s, c1 = (khalf * 2 + 1) ^ s;
  *(uint4*)(bufA + (row << 5) + c0 * 8) = make_uint4(pk[0], pk[1], pk[2], pk[3]);
  *(uint4*)(bufA + (row << 5) + c1 * 8) = make_uint4(pk[4], pk[5], pk[6], pk[7]);
}

// fragment read: 16B at (row, k-chunk lg), chunk XOR ((row>>1)&3)
__device__ __forceinline__ s16x8 frag_read(const unsigned short* buf, int row, int lg) {
  int cr = lg ^ ((row >> 1) & 3);
  return *(const s16x8*)(buf + row * 32 + cr * 8);
}

// One K-tile, 2 phases. vmcnt ledger (steady): entering ph1 = {A(T+2)f32:4,
// B(T+1):2, A(T+3):4, B(T+2):2} = 12 -> VMC(6) retires A(T+2)+B(T+1) BEFORE the
// ph1 barrier (publishes B(T+1) wave-wide for ph2's pre-read). ph2 issues
// A(T+4):4 + B(T+3):2 -> back to 12.
template<bool PRE, bool CVT, bool AISS, bool BST, int VM>
__device__ __forceinline__ void tile_one(
    int kt, const float* gA, const unsigned short* gB,
    unsigned short* sA, unsigned short* sB, f32x4 (&acc)[8][4],
    s16x8 (&fa03)[4], s16x8 (&fa47)[4], s16x8 (&fb)[4], f32x4 (&aset)[4],
    int w, int lane, int wr, int wc, int l15, int lg, int arow, int akh) {
  // ---------- ph1
  LGKM0(); SB0();
  __builtin_amdgcn_s_setprio(1);
#pragma unroll
  for (int m = 0; m < 4; ++m)
#pragma unroll
    for (int n = 0; n < 4; ++n)
      acc[m][n] = __builtin_amdgcn_mfma_f32_16x16x32_bf16(fa03[m], fb[n], acc[m][n], 0, 0, 0);
  __builtin_amdgcn_s_setprio(0);
  SB0();
  if constexpr (VM == 6) { VMC(6); }
  else if constexpr (VM == 2) { VMC(2); }
  else if constexpr (VM == 0) { VMC(0); }
  if (CVT) {
    cvtwriteA(aset, sA + ((kt + 2) & 3) * 8192, arow, akh);
    SB0();                     // pin: writes issue before the fa47 reads
  }
  {
    const unsigned short* pA = sA + (kt & 3) * 8192;
#pragma unroll
    for (int i = 0; i < 4; ++i) fa47[i] = frag_read(pA, wr * 128 + (4 + i) * 16 + l15, lg);
  }
  if (CVT) { LGKMC(4); }       // retire the 2 ds_writes (DS in-order); reads stay
  BAR();
  // ---------- ph2
  LGKM0(); SB0();
  __builtin_amdgcn_s_setprio(1);
#pragma unroll
  for (int m = 0; m < 4; ++m)
#pragma unroll
    for (int n = 0; n < 4; ++n)
      acc[4 + m][n] = __builtin_amdgcn_mfma_f32_16x16x32_bf16(fa47[m], fb[n], acc[4 + m][n], 0, 0, 0);
  __builtin_amdgcn_s_setprio(0);
  SB0();
  if (PRE) {
    const unsigned short* qA = sA + ((kt + 1) & 3) * 8192;
    const unsigned short* qB = sB + ((kt + 1) & 3) * 8192;
#pragma unroll
    for (int i = 0; i < 4; ++i) fa03[i] = frag_read(qA, wr * 128 + i * 16 + l15, lg);
#pragma unroll
    for (int n = 0; n < 4; ++n) fb[n] = frag_read(qB, wc * 64 + n * 16 + l15, lg);
  }
  if (AISS) loadA(gA, kt + 4, arow, akh, aset);
  if (BST)  stageB(gB + (size_t)(kt + 3) * 32, sB + ((kt + 3) & 3) * 8192, w, lane);
  BAR();
}

// 256x256 tile, BK=32, quad-buffered bf16 LDS; A converted f32->bf16 in-kernel.
__global__ __launch_bounds__(512, 2) void k_score_gemm(
    const float* __restrict__ values, const unsigned short* __restrict__ W2t,
    const float* __restrict__ add2, const float* __restrict__ Vk,
    float* __restrict__ score_part) {
  __shared__ unsigned short sA[32768];   // 4 bufs x 256 x 32 bf16
  __shared__ unsigned short sB[32768];
  const int tid = threadIdx.x;
  const int w = tid >> 6, lane = tid & 63;
  const int wr = w >> 2, wc = w & 3;     // 2M x 4N waves, wave-tile 128x64
  const int l15 = lane & 15, lg = lane >> 4;
  const int arow = tid >> 1, akh = tid & 1;

  const int L = blockIdx.x;
  const int g = (L & 7) * 128 + (L >> 3);   // XCD-contiguous: 4 ntiles share A strip
  const int mtile = g >> 2, ntile = g & 3;

  const float* gA = values + ((size_t)mtile << 18);          // 256 rows x 1024 f32
  const unsigned short* gB = W2t + ((size_t)ntile << 18);    // 256 rows x 1024 bf16

  f32x4 acc[8][4] = {};
  s16x8 fa03[4], fa47[4], fb[4];
  f32x4 aset0[4], aset1[4];

  // Prologue: A(0),A(1) cvt'd to LDS; B(0..2) staged; A(2),A(3) f32 in regs.
  {
    f32x4 t[4];
    loadA(gA, 0, arow, akh, t);
    cvtwriteA(t, sA, arow, akh);
    loadA(gA, 1, arow, akh, t);
    cvtwriteA(t, sA + 8192, arow, akh);
    stageB(gB, sB, w, lane);
    stageB(gB + 32, sB + 8192, w, lane);
    stageB(gB + 64, sB + 16384, w, lane);
    loadA(gA, 2, arow, akh, aset0);
    loadA(gA, 3, arow, akh, aset1);
    VMC(8);    // retire B(0..2); A(2),A(3) stay in flight
    LGKM0();
    BAR();
  }
#pragma unroll
  for (int i = 0; i < 4; ++i) fa03[i] = frag_read(sA, wr * 128 + i * 16 + l15, lg);
#pragma unroll
  for (int n = 0; n < 4; ++n) fb[n] = frag_read(sB, wc * 64 + n * 16 + l15, lg);

#pragma unroll 1
  for (int kt = 0; kt < 28; kt += 2) {
    tile_one<1, 1, 1, 1, 6>(kt,     gA, gB, sA, sB, acc, fa03, fa47, fb, aset0,
                            w, lane, wr, wc, l15, lg, arow, akh);
    tile_one<1, 1, 1, 1, 6>(kt + 1, gA, gB, sA, sB, acc, fa03, fa47, fb, aset1,
                            w, lane, wr, wc, l15, lg, arow, akh);
  }
  tile_one<1, 1, 0, 1, 6>(28, gA, gB, sA, sB, acc, fa03, fa47, fb, aset0,
                          w, lane, wr, wc, l15, lg, arow, akh);
  tile_one<1, 1, 0, 0, 2>(29, gA, gB, sA, sB, acc, fa03, fa47, fb, aset1,
                          w, lane, wr, wc, l15, lg, arow, akh);
  tile_one<1, 0, 0, 0, 0>(30, gA, gB, sA, sB, acc, fa03, fa47, fb, aset0,
                          w, lane, wr, wc, l15, lg, arow, akh);
  tile_one<0, 0, 0, 0, -1>(31, gA, gB, sA, sB, acc, fa03, fa47, fb, aset1,
                           w, lane, wr, wc, l15, lg, arow, akh);

  // Epilogue: x = acc + add2[b][u]; row-sum of tanh(x)*Vk[u] over this 256-col slab
  const int b = (mtile * 256) >> 11;   // block-uniform
  float vks[4], adds[4];
#pragma unroll
  for (int n = 0; n < 4; ++n) {
    int u = ntile * 256 + wc * 64 + n * 16 + l15;
    vks[n] = Vk[u];
    adds[n] = add2[(b << 10) + u];
  }
  __syncthreads();
  float* part = (float*)sA;   // [4][256]
#pragma unroll
  for (int m = 0; m < 8; ++m) {
#pragma unroll
    for (int j = 0; j < 4; ++j) {
      float s = 0.f;
#pragma unroll
      for (int n = 0; n < 4; ++n) {
        float x = acc[m][n][j] + adds[n];
        s = fmaf(tanh_fast(x), vks[n], s);
      }
#pragma unroll
      for (int off = 1; off < 16; off <<= 1) s += __shfl_xor(s, off);
      if (l15 == 0) part[wc * 256 + wr * 128 + m * 16 + lg * 4 + j] = s;
    }
  }
  __syncthreads();
  if (tid < 256) {
    float v = part[tid] + part[256 + tid] + part[512 + tid] + part[768 + tid];
    score_part[((size_t)ntile << 16) + mtile * 256 + tid] = v;
  }
}

// add2[b][u] = query[b]·W1_k[:,u] + W1_b[u] + W2_b[u]
__global__ void k_qproj(const float* __restrict__ q, const float* __restrict__ W1,
                        const float* __restrict__ W1b, const float* __restrict__ W2b,
                        float* __restrict__ add2) {
  int u = blockIdx.x * 256 + threadIdx.x;
  int b = blockIdx.y;
  const float* qr = q + (b << 10);
  float s = 0.f;
#pragma unroll 8
  for (int d = 0; d < ND; ++d) s = fmaf(qr[d], W1[d * NU + u], s);
  add2[(b << 10) + u] = s + W1b[u] + W2b[u];
}

// W2_k [D][U] f32 -> W2t [U][D] bf16
__global__ void k_w2t(const float* __restrict__ W2, unsigned short* __restrict__ W2t) {
  __shared__ unsigned short tile[64][65];
  int bu = blockIdx.x * 64, bd = blockIdx.y * 64;
  int x = threadIdx.x & 63, y4 = threadIdx.x >> 6;
#pragma unroll
  for (int r = 0; r < 16; ++r) {
    int dl = y4 * 16 + r;
    tile[x][dl] = f2bf(W2[(size_t)(bd + dl) * NU + bu + x]);
  }
  __syncthreads();
#pragma unroll
  for (int r = 0; r < 16; ++r) {
    int ul = y4 * 16 + r;
    W2t[(size_t)(bu + ul) * ND + bd + x] = tile[ul][x];
  }
}

// softmax over T per batch; sums 4 N-tile partials first (deterministic)
__global__ void k_softmax(const float* __restrict__ sp, float* __restrict__ w) {
  __shared__ float redm[4], reds[4];
  int b = blockIdx.x, tid = threadIdx.x;
  float s[8];
  float mx = -1e30f;
#pragma unroll
  for (int i = 0; i < 8; ++i) {
    int t = i * 256 + tid;
    float v = 0.f;
#pragma unroll
    for (int p = 0; p < 4; ++p) v += sp[((size_t)p << 16) + (b << 11) + t];
    s[i] = v;
    mx = fmaxf(mx, v);
  }
#pragma unroll
  for (int o = 1; o < 64; o <<= 1) mx = fmaxf(mx, __shfl_xor(mx, o));
  if ((tid & 63) == 0) redm[tid >> 6] = mx;
  __syncthreads();
  mx = fmaxf(fmaxf(redm[0], redm[1]), fmaxf(redm[2], redm[3]));
  float sum = 0.f;
#pragma unroll
  for (int i = 0; i < 8; ++i) { s[i] = __expf(s[i] - mx); sum += s[i]; }
#pragma unroll
  for (int o = 1; o < 64; o <<= 1) sum += __shfl_xor(sum, o);
  if ((tid & 63) == 0) reds[tid >> 6] = sum;
  __syncthreads();
  float inv = 1.0f / (reds[0] + reds[1] + reds[2] + reds[3]);
#pragma unroll
  for (int i = 0; i < 8; ++i) w[(b << 11) + i * 256 + tid] = s[i] * inv;
}

// context partials over 16 t-chunks of 128: part[tc][b][d]
__global__ void k_context(const float* __restrict__ values, const float* __restrict__ wv,
                          float* __restrict__ part) {
  int d4 = threadIdx.x;
  int b = blockIdx.y, tc = blockIdx.z;
  const float4* vb = (const float4*)(values + ((size_t)b << 21) + ((size_t)tc << 17)) + d4;
  const float* wb = wv + (b << 11) + (tc << 7);
  float ax = 0.f, ay = 0.f, az = 0.f, aw = 0.f;
#pragma unroll 4
  for (int t = 0; t < 128; ++t) {
    float4 v = vb[(size_t)t << 8];
    float wt = wb[t];
    ax = fmaf(wt, v.x, ax); ay = fmaf(wt, v.y, ay);
    az = fmaf(wt, v.z, az); aw = fmaf(wt, v.w, aw);
  }
  float4* po = (float4*)(part + (((size_t)tc * NB + b) << 10)) + d4;
  *po = make_float4(ax, ay, az, aw);
}

__global__ void k_ctx_reduce(const float* __restrict__ part, float* __restrict__ out) {
  int i = blockIdx.x * 256 + threadIdx.x;  // 32768
  float s = 0.f;
#pragma unroll
  for (int p = 0; p < 16; ++p) s += part[(p << 15) + i];
  out[i] = s;
}

extern "C" void kernel_launch(void* const* d_in, const int* in_sizes, int n_in,
                              void* d_out, int out_size, void* d_ws, size_t ws_size,
                              hipStream_t stream) {
  const float* query  = (const float*)d_in[0];
  const float* values = (const float*)d_in[1];
  const float* W1k    = (const float*)d_in[2];
  const float* W1b    = (const float*)d_in[3];
  const float* W2k    = (const float*)d_in[4];
  const float* W2b    = (const float*)d_in[5];
  const float* Vk     = (const float*)d_in[6];
  // V_b dropped: softmax is shift-invariant.
  float* out = (float*)d_out;
  char* ws = (char*)d_ws;

  size_t off = 0;
  float* add2 = (float*)(ws + off); off += (size_t)NB * NU * 4;            // 128 KB
  float* sp   = (float*)(ws + off); off += (size_t)4 * NM * 4;             // 1 MB
  float* wv   = (float*)(ws + off); off += (size_t)NM * 4;                 // 256 KB
  float* ctxp = (float*)(ws + off); off += (size_t)16 * NB * ND * 4;       // 2 MB
  unsigned short* W2t = (unsigned short*)(ws + off); off += (size_t)NU * ND * 2; // 2 MB

  k_qproj<<<dim3(4, 32), 256, 0, stream>>>(query, W1k, W1b, W2b, add2);
  k_w2t<<<dim3(16, 16), 256, 0, stream>>>(W2k, W2t);
  k_score_gemm<<<dim3(1024), 512, 0, stream>>>(values, W2t, add2, Vk, sp);
  k_softmax<<<dim3(32), 256, 0, stream>>>(sp, wv);
  k_context<<<dim3(1, 32, 16), 256, 0, stream>>>(values, wv, ctxp);
  k_ctx_reduce<<<dim3(128), 256, 0, stream>>>(ctxp, out);
}